// Round 3
// baseline (2820.631 us; speedup 1.0000x reference)
//
#include <hip/hip_runtime.h>
#include <math.h>
#include <stdint.h>

namespace {

constexpr int T = 50;
constexpr int NB = 32768;
constexpr int H = 128;
constexpr int NTHREADS = 512;   // 8 waves, 16 rows each
constexpr int BLK_ROWS = 128;   // rows per block

typedef float v4f __attribute__((ext_vector_type(4)));
typedef float v2f __attribute__((ext_vector_type(2)));
typedef short short8 __attribute__((ext_vector_type(8)));

union FU { float f; uint32_t u; };
union U8 { uint32_t u[4]; short8 v; };

__device__ __forceinline__ uint32_t pack_hi16(uint32_t odd, uint32_t even) {
  return (odd & 0xFFFF0000u) | (even >> 16);
}

// 2-way bf16 split: a ~= bf16(hi) + bf16(mid), |residual| <= 2^-16 |a|
__device__ __forceinline__ void split2(float a, uint32_t& hi, uint32_t& mid) {
  FU c0; c0.f = a;
  uint32_t uh = c0.u & 0xFFFF0000u;
  FU fh; fh.u = uh;
  float r1 = a - fh.f;              // exact
  FU c1; c1.f = r1;
  hi = uh; mid = c1.u & 0xFFFF0000u;
}

__device__ __forceinline__ v4f mfma16(short8 a, short8 b, v4f c) {
  return __builtin_amdgcn_mfma_f32_16x16x32_bf16(a, b, c, 0, 0, 0);
}

__global__ __launch_bounds__(NTHREADS, 2)
void fwdsim3(const float* __restrict__ proj,   // (B, 64)
             const float* __restrict__ idm,    // (B, T, 12)
             const float* __restrict__ merg,   // (B, T, 3)
             const float* __restrict__ W1,     // (73, 128)
             const float* __restrict__ b1,     // (128)
             const float* __restrict__ W2,     // (128, 128)
             const float* __restrict__ b2,     // (128)
             const float* __restrict__ W3,     // (128, 1)
             const float* __restrict__ b3,     // (1)
             const float* __restrict__ smean,  // (6)
             const float* __restrict__ svar,   // (6)
             float* __restrict__ out)          // (B, T)
{
  // W2 as 2 bf16 split planes, frag-ordered: [(kt*8+nt)*128 + plane*64 + lane]
  __shared__ short8 sB[4 * 8 * 2 * 64];   // 64 KiB

  const int tid  = threadIdx.x;
  const int wave = tid >> 6;
  const int lane = tid & 63;
  const int g    = lane >> 4;   // 0..3
  const int o    = lane & 15;   // 0..15
  const int wave_row0 = blockIdx.x * BLK_ROWS + wave * 16;
  const int row  = wave_row0 + o;   // the batch row this lane owns (x4 g-replicated)

  // ---- stage W2 split planes into LDS (frag layout, verified in R2) ----
  for (int job = tid; job < 2048; job += NTHREADS) {
    const int lj   = job & 63;
    const int ktnt = job >> 6;                    // kt*8 + nt
    const int k0   = (ktnt >> 3) * 32 + (lj >> 4) * 8;
    const int n    = (ktnt & 7) * 16 + (lj & 15);
    uint32_t hi[8], mi[8];
#pragma unroll
    for (int j = 0; j < 8; ++j) split2(W2[(k0 + j) * H + n], hi[j], mi[j]);
    U8 fh, fm;
#pragma unroll
    for (int d = 0; d < 4; ++d) {
      fh.u[d] = pack_hi16(hi[2*d+1], hi[2*d]);
      fm.u[d] = pack_hi16(mi[2*d+1], mi[2*d]);
    }
    sB[ktnt * 128 + lj]      = fh.v;
    sB[ktnt * 128 + 64 + lj] = fm.v;
  }

  // ---- per-lane constants ----
  float mean[6], istd[6];
#pragma unroll
  for (int c = 0; c < 6; ++c) { mean[c] = smean[c]; istd[c] = 1.0f / sqrtf(svar[c]); }
  const float b3v = b3[0];
  float b2r[8], W3r[8];
#pragma unroll
  for (int nt = 0; nt < 8; ++nt) { b2r[nt] = b2[nt*16 + o]; W3r[nt] = W3[nt*16 + o]; }

  // ---- base1 = b1 + proj[row] @ W1[0:64], at this lane's frag coords ----
  // base[kt][:] covers cols kt*32 + 8g .. +7  (exactly the A-frag k-slice)
  v4f base[4][2];
#pragma unroll
  for (int kt = 0; kt < 4; ++kt) {
    base[kt][0] = *(const v4f*)(b1 + kt*32 + 8*g);
    base[kt][1] = *(const v4f*)(b1 + kt*32 + 8*g + 4);
  }
  {
    const float* prow = proj + (size_t)row * 64;
    for (int k4 = 0; k4 < 16; ++k4) {
      v4f p = *(const v4f*)(prow + 4*k4);
#pragma unroll
      for (int e = 0; e < 4; ++e) {
        const float* wr = W1 + (k4*4 + e) * H + 8*g;
        const float pe = p[e];
#pragma unroll
        for (int kt = 0; kt < 4; ++kt) {
          base[kt][0] += pe * *(const v4f*)(wr + kt*32);
          base[kt][1] += pe * *(const v4f*)(wr + kt*32 + 4);
        }
      }
    }
  }
  __syncthreads();   // sB ready; NO barriers in the t-loop (sB read-only, no shared h)

  // ---- recurrent state for row `row` (replicated across the 4 g-copies) ----
  float ego_v = 0.f, ego_x = 0.f, act = 0.f;
  const float* idm_row = idm  + (size_t)row * (T * 12);
  const float* mrg_row = merg + (size_t)row * (T * 3);

  v4f  sa;  v2f fb;  float ex, mc0, mc1, mc2;        // current step inputs
  v4f  nsa; v2f nfb; float nex, nmc0, nmc1, nmc2;    // prefetched next step
  {
    const float* ip = idm_row;
    sa = *(const v4f*)ip;  fb = *(const v2f*)(ip + 4);  ex = ip[11];
    mc0 = mrg_row[0]; mc1 = mrg_row[1]; mc2 = mrg_row[2];
  }

  const float* w1e_base = W1 + 64 * H + 8 * g;   // env rows of W1, this lane's g-offset

#pragma unroll 1
  for (int t = 0; t < T; ++t) {
    // ---- state update + env features (fp32) ----
    const float s0 = sa[0], fv = sa[1], mv = sa[2], s3 = sa[3];
    const float fgx = fb[0], mgx = fb[1];
    if (t == 0) { ego_v = s0; ego_x = s3; }
    else {
      ego_v += act * 0.1f;
      ego_x += ego_v * 0.1f + act * 0.005f;   // 0.5*act*0.1^2
    }
    float xk[9];
    xk[0] = (ego_v                                     - mean[0]) * istd[0];
    xk[1] = (fv                                        - mean[1]) * istd[1];
    xk[2] = (ego_v - fv                                - mean[2]) * istd[2];
    xk[3] = (fgx - ego_x                               - mean[3]) * istd[3];
    xk[4] = ((ego_v - mv) * ex                         - mean[4]) * istd[4];
    xk[5] = ((mgx - ego_x) * ex + (1.0f - ex) * 100.0f - mean[5]) * istd[5];
    xk[6] = mc0; xk[7] = mc1; xk[8] = mc2;

    // prefetch next step's inputs (independent; overlaps layer-1 + MFMA)
    if (t + 1 < T) {
      const float* ip = idm_row + (t + 1) * 12;
      nsa = *(const v4f*)ip;  nfb = *(const v2f*)(ip + 4);  nex = ip[11];
      const float* mp = mrg_row + (t + 1) * 3;
      nmc0 = mp[0]; nmc1 = mp[1]; nmc2 = mp[2];
    }

    // ---- layer 1 at A-frag coords: h[row=o][kt*32+8g+j], j=0..7 per kt ----
    short8 ah[4], am[4];
#pragma unroll
    for (int kt = 0; kt < 4; ++kt) {
      v4f h0 = base[kt][0], h1 = base[kt][1];
      const float* wp = w1e_base + kt * 32;
#pragma unroll
      for (int k = 0; k < 9; ++k) {
        v4f w0  = *(const v4f*)(wp + k * H);       // global, L1-resident (4.6 KB)
        v4f w1v = *(const v4f*)(wp + k * H + 4);
        h0 += xk[k] * w0;
        h1 += xk[k] * w1v;
      }
#pragma unroll
      for (int e = 0; e < 4; ++e) { h0[e] = fmaxf(h0[e], 0.f); h1[e] = fmaxf(h1[e], 0.f); }
      uint32_t hi[8], mi[8];
#pragma unroll
      for (int e = 0; e < 4; ++e) split2(h0[e], hi[e],   mi[e]);
#pragma unroll
      for (int e = 0; e < 4; ++e) split2(h1[e], hi[4+e], mi[4+e]);
      U8 uh, um;
#pragma unroll
      for (int d = 0; d < 4; ++d) {
        uh.u[d] = pack_hi16(hi[2*d+1], hi[2*d]);
        um.u[d] = pack_hi16(mi[2*d+1], mi[2*d]);
      }
      ah[kt] = uh.v; am[kt] = um.v;
    }

    // ---- layer 2: h2 = relu(h1 @ W2 + b2), 3-term split MFMA ----
    v4f acc[8];
#pragma unroll
    for (int nt = 0; nt < 8; ++nt) acc[nt] = (v4f){b2r[nt], b2r[nt], b2r[nt], b2r[nt]};
#pragma unroll
    for (int kt = 0; kt < 4; ++kt) {
#pragma unroll
      for (int nt = 0; nt < 8; ++nt) {
        const int bb = (kt * 8 + nt) * 128 + lane;
        short8 bh = sB[bb];
        short8 bm = sB[bb + 64];
        acc[nt] = mfma16(ah[kt], bm, acc[nt]);   // ~2^-9 term
        acc[nt] = mfma16(am[kt], bh, acc[nt]);   // ~2^-9 term
        acc[nt] = mfma16(ah[kt], bh, acc[nt]);   // O(1) term
      }
    }

    // ---- layer 3: act = relu(h2) @ W3 + b3 ----
    float part[4];   // r -> row 4g + r (C layout)
#pragma unroll
    for (int r = 0; r < 4; ++r) part[r] = 0.f;
#pragma unroll
    for (int nt = 0; nt < 8; ++nt) {
      v4f h = acc[nt];
#pragma unroll
      for (int r = 0; r < 4; ++r) part[r] += fmaxf(h[r], 0.f) * W3r[nt];
    }
#pragma unroll
    for (int m = 1; m <= 8; m <<= 1) {
#pragma unroll
      for (int r = 0; r < 4; ++r) part[r] += __shfl_xor(part[r], m, 64);
    }
    // gather act for row `o`: held by g' = o>>2 group, reg r' = o&3
    const int src = ((o >> 2) << 4) | o;
    const float c0 = __shfl(part[0], src, 64);
    const float c1 = __shfl(part[1], src, 64);
    const float c2 = __shfl(part[2], src, 64);
    const float c3 = __shfl(part[3], src, 64);
    const float slo = (o & 1) ? c1 : c0;
    const float shi = (o & 1) ? c3 : c2;
    act = ((o & 2) ? shi : slo) + b3v;   // replicated in all 4 g-copies

    if (g == 0) out[(size_t)row * T + t] = act;

    // roll staged inputs
    sa = nsa; fb = nfb; ex = nex; mc0 = nmc0; mc1 = nmc1; mc2 = nmc2;
  }
}

}  // namespace

extern "C" void kernel_launch(void* const* d_in, const int* in_sizes, int n_in,
                              void* d_out, int out_size, void* d_ws, size_t ws_size,
                              hipStream_t stream) {
  const float* proj  = (const float*)d_in[0];
  const float* idm   = (const float*)d_in[1];
  const float* merg  = (const float*)d_in[2];
  const float* W1    = (const float*)d_in[3];
  const float* b1    = (const float*)d_in[4];
  const float* W2    = (const float*)d_in[5];
  const float* b2    = (const float*)d_in[6];
  const float* W3    = (const float*)d_in[7];
  const float* b3    = (const float*)d_in[8];
  const float* smean = (const float*)d_in[9];
  const float* svar  = (const float*)d_in[10];
  // d_in[11] = rollout_len (fixed 50)

  dim3 grid(NB / BLK_ROWS);   // 256 blocks -> 1 per CU, single pass
  dim3 block(NTHREADS);       // 512 threads = 8 waves x 16 rows
  hipLaunchKernelGGL(fwdsim3, grid, block, 0, stream,
                     proj, idm, merg, W1, b1, W2, b2, W3, b3, smean, svar,
                     (float*)d_out);
}

// Round 4
// 437.112 us; speedup vs baseline: 6.4529x; 6.4529x over previous
//
#include <hip/hip_runtime.h>
#include <math.h>
#include <stdint.h>

namespace {

constexpr int T = 50;
constexpr int NB = 32768;
constexpr int H = 128;
constexpr int NTHREADS = 256;   // 4 waves
constexpr int BLK_ROWS = 128;   // 4 waves x 32 rows (2 M-tiles of 16)

typedef float v4f __attribute__((ext_vector_type(4)));
typedef float v2f __attribute__((ext_vector_type(2)));
typedef unsigned int v4u __attribute__((ext_vector_type(4)));
typedef short short8 __attribute__((ext_vector_type(8)));

union FU { float f; uint32_t u; };
union U8 { uint32_t u[4]; short8 v; };

__device__ __forceinline__ uint32_t pack_hi16(uint32_t odd, uint32_t even) {
  return (odd & 0xFFFF0000u) | (even >> 16);
}
__device__ __forceinline__ uint32_t pack_lo16(uint32_t odd, uint32_t even) {
  return (odd << 16) | (even & 0xFFFFu);
}

// 2-way bf16 split (truncation): a ~= bf16(hi)+bf16(mid), residual <= 2^-16 |a|
__device__ __forceinline__ void split2(float a, uint32_t& hi, uint32_t& mid) {
  FU c0; c0.f = a;
  uint32_t uh = c0.u & 0xFFFF0000u;
  FU fh; fh.u = uh;
  float r1 = a - fh.f;   // exact
  FU c1; c1.f = r1;
  hi = uh; mid = c1.u & 0xFFFF0000u;
}
// 3-way exact bf16 split
__device__ __forceinline__ void split3(float a, uint32_t& hi, uint32_t& mid, uint32_t& lo) {
  FU c0; c0.f = a;
  uint32_t uh = c0.u & 0xFFFF0000u;
  FU fh; fh.u = uh;
  float r1 = a - fh.f;
  FU c1; c1.f = r1;
  uint32_t um = c1.u & 0xFFFF0000u;
  FU fm; fm.u = um;
  float r2 = r1 - fm.f;
  FU c2; c2.f = r2;
  hi = uh; mid = um; lo = c2.u;
}

__device__ __forceinline__ v4f mfma16(short8 a, short8 b, v4f c) {
  return __builtin_amdgcn_mfma_f32_16x16x32_bf16(a, b, c, 0, 0, 0);
}

__global__ __launch_bounds__(NTHREADS, 1)
void fwdsim4(const float* __restrict__ proj,   // (B, 64)
             const float* __restrict__ idm,    // (B, T, 12)
             const float* __restrict__ merg,   // (B, T, 3)
             const float* __restrict__ W1,     // (73, 128)
             const float* __restrict__ b1,     // (128)
             const float* __restrict__ W2,     // (128, 128)
             const float* __restrict__ b2,     // (128)
             const float* __restrict__ W3,     // (128, 1)
             const float* __restrict__ b3,     // (1)
             const float* __restrict__ smean,  // (6)
             const float* __restrict__ svar,   // (6)
             float* __restrict__ out)          // (B, T)
{
  // W1[0:64] 3-plane bf16 frags (prologue-only use): [kt*8+nt][plane][lane]
  __shared__ short8 sW1b[16 * 3 * 64];          // 49152 B
  // W1 env rows 64..72 (zero-padded to K=32), 2-plane frags: [nt][plane][lane]
  __shared__ short8 sEnvB[8 * 2 * 64];          // 16384 B
  // base1 (b1 + proj@W1[0:64]) fp32, [wave][col(128)][row padded to 36]
  __shared__ float sBase[4 * 128 * 36];         // 73728 B
  // per-step h slice, packed bf16 hi|mid: [wave][row(32)][k padded to 36]
  __shared__ uint32_t sH[4 * 32 * 36];          // 18432 B
  // total 157696 B <= 160 KiB

  const int tid  = threadIdx.x;
  const int wave = tid >> 6;
  const int lane = tid & 63;
  const int gq   = lane >> 4;   // 0..3
  const int o    = lane & 15;   // 0..15
  const int wave_row0 = blockIdx.x * BLK_ROWS + wave * 32;

  // ---- stage W1[0:64] 3-plane frags ----
  for (int job = tid; job < 1024; job += NTHREADS) {
    const int lj = job & 63, ktnt = job >> 6;
    const int k0 = (ktnt >> 3) * 32 + (lj >> 4) * 8;
    const int n  = (ktnt & 7) * 16 + (lj & 15);
    uint32_t hi[8], mi[8], lo[8];
#pragma unroll
    for (int j = 0; j < 8; ++j) split3(W1[(k0 + j) * H + n], hi[j], mi[j], lo[j]);
    U8 fh, fm, fl;
#pragma unroll
    for (int d = 0; d < 4; ++d) {
      fh.u[d] = pack_hi16(hi[2*d+1], hi[2*d]);
      fm.u[d] = pack_hi16(mi[2*d+1], mi[2*d]);
      fl.u[d] = pack_hi16(lo[2*d+1], lo[2*d]);
    }
    sW1b[(ktnt * 3 + 0) * 64 + lj] = fh.v;
    sW1b[(ktnt * 3 + 1) * 64 + lj] = fm.v;
    sW1b[(ktnt * 3 + 2) * 64 + lj] = fl.v;
  }
  // ---- stage W1env 2-plane frags (k = 0..8 live, rest zero) ----
  for (int job = tid; job < 512; job += NTHREADS) {
    const int lj = job & 63, nt = job >> 6;
    const int k0 = (lj >> 4) * 8;
    const int n  = nt * 16 + (lj & 15);
    uint32_t hi[8], mi[8];
#pragma unroll
    for (int j = 0; j < 8; ++j) {
      const int k = k0 + j;
      const float w = (k < 9) ? W1[(64 + k) * H + n] : 0.f;
      split2(w, hi[j], mi[j]);
    }
    U8 fh, fm;
#pragma unroll
    for (int d = 0; d < 4; ++d) {
      fh.u[d] = pack_hi16(hi[2*d+1], hi[2*d]);
      fm.u[d] = pack_hi16(mi[2*d+1], mi[2*d]);
    }
    sEnvB[(nt * 2 + 0) * 64 + lj] = fh.v;
    sEnvB[(nt * 2 + 1) * 64 + lj] = fm.v;
  }

  // ---- W2 -> persistent register B-frags (AGPR-legal: written once, MFMA-only) ----
  short8 w2h[32], w2m[32];   // [kt*8+nt], 2 planes = 256 regs
#pragma unroll
  for (int ktnt = 0; ktnt < 32; ++ktnt) {
    const int k0 = (ktnt >> 3) * 32 + gq * 8;
    const int n  = (ktnt & 7) * 16 + o;
    uint32_t hi[8], mi[8];
#pragma unroll
    for (int j = 0; j < 8; ++j) split2(W2[(k0 + j) * H + n], hi[j], mi[j]);
    U8 fh, fm;
#pragma unroll
    for (int d = 0; d < 4; ++d) {
      fh.u[d] = pack_hi16(hi[2*d+1], hi[2*d]);
      fm.u[d] = pack_hi16(mi[2*d+1], mi[2*d]);
    }
    w2h[ktnt] = fh.v;
    w2m[ktnt] = fm.v;
  }

  // ---- scalars ----
  float mean[6], istd[6];
#pragma unroll
  for (int c = 0; c < 6; ++c) { mean[c] = smean[c]; istd[c] = 1.0f / sqrtf(svar[c]); }
  const float b3v = b3[0];
  float b2c[8], W3c[8];
#pragma unroll
  for (int nt = 0; nt < 8; ++nt) { b2c[nt] = b2[nt*16 + o]; W3c[nt] = W3[nt*16 + o]; }

  __syncthreads();   // frag planes ready

  // ---- base1 = b1 + proj @ W1[0:64] via 6-term exact-split MFMA -> sBase ----
#pragma unroll
  for (int mt = 0; mt < 2; ++mt) {
    const int row = wave_row0 + mt * 16 + o;
    short8 pah[2], pam[2], pal[2];
#pragma unroll
    for (int kt = 0; kt < 2; ++kt) {
      const float* pp = proj + (size_t)row * 64 + kt * 32 + gq * 8;
      v4f p0 = *(const v4f*)pp;
      v4f p1 = *(const v4f*)(pp + 4);
      uint32_t hi[8], mi[8], lo[8];
#pragma unroll
      for (int e = 0; e < 4; ++e) split3(p0[e], hi[e],   mi[e],   lo[e]);
#pragma unroll
      for (int e = 0; e < 4; ++e) split3(p1[e], hi[4+e], mi[4+e], lo[4+e]);
      U8 uh, um, ul;
#pragma unroll
      for (int d = 0; d < 4; ++d) {
        uh.u[d] = pack_hi16(hi[2*d+1], hi[2*d]);
        um.u[d] = pack_hi16(mi[2*d+1], mi[2*d]);
        ul.u[d] = pack_hi16(lo[2*d+1], lo[2*d]);
      }
      pah[kt] = uh.v; pam[kt] = um.v; pal[kt] = ul.v;
    }
    v4f acc[8];
#pragma unroll
    for (int nt = 0; nt < 8; ++nt) {
      const float bb = b1[nt * 16 + o];
      acc[nt] = (v4f){bb, bb, bb, bb};
    }
#pragma unroll
    for (int kt = 0; kt < 2; ++kt)
#pragma unroll
      for (int nt = 0; nt < 8; ++nt) {
        short8 bh = sW1b[((kt*8+nt)*3 + 0) * 64 + lane];
        short8 bm = sW1b[((kt*8+nt)*3 + 1) * 64 + lane];
        short8 bl = sW1b[((kt*8+nt)*3 + 2) * 64 + lane];
        acc[nt] = mfma16(pah[kt], bl, acc[nt]);
        acc[nt] = mfma16(pal[kt], bh, acc[nt]);
        acc[nt] = mfma16(pam[kt], bm, acc[nt]);
        acc[nt] = mfma16(pah[kt], bm, acc[nt]);
        acc[nt] = mfma16(pam[kt], bh, acc[nt]);
        acc[nt] = mfma16(pah[kt], bh, acc[nt]);
      }
#pragma unroll
    for (int nt = 0; nt < 8; ++nt) {
      float* dst = &sBase[(wave * 128 + nt*16 + o) * 36 + mt*16 + 4*gq];
      *(v4f*)dst = acc[nt];   // C layout: rows 4gq+r, col nt*16+o
    }
  }

  // ---- recurrent state: lane owns rows o (Mt0), 16+o (Mt1), replicated over gq ----
  float ego_v[2], ego_x[2], act[2] = {0.f, 0.f};
  const float* idmp[2] = { idm + (size_t)(wave_row0 + o) * (T*12),
                           idm + (size_t)(wave_row0 + 16 + o) * (T*12) };
  const float* mrgp[2] = { merg + (size_t)(wave_row0 + o) * (T*3),
                           merg + (size_t)(wave_row0 + 16 + o) * (T*3) };
  v4f sa[2]; v2f fb[2]; float exr[2], m0[2], m1[2], m2[2];
  v4f nsa[2]; v2f nfb[2]; float nex[2], nm0[2], nm1[2], nm2[2];
#pragma unroll
  for (int mt = 0; mt < 2; ++mt) {
    sa[mt] = *(const v4f*)idmp[mt];
    fb[mt] = *(const v2f*)(idmp[mt] + 4);
    exr[mt] = idmp[mt][11];
    m0[mt] = mrgp[mt][0]; m1[mt] = mrgp[mt][1]; m2[mt] = mrgp[mt][2];
  }

#pragma unroll 1
  for (int t = 0; t < T; ++t) {
    // ---- state + env ----
    float xk[2][9];
#pragma unroll
    for (int mt = 0; mt < 2; ++mt) {
      const float s0 = sa[mt][0], fv = sa[mt][1], mv = sa[mt][2], s3 = sa[mt][3];
      const float fgx = fb[mt][0], mgx = fb[mt][1];
      const float ex = exr[mt];
      if (t == 0) { ego_v[mt] = s0; ego_x[mt] = s3; }
      else {
        ego_v[mt] += act[mt] * 0.1f;
        ego_x[mt] += ego_v[mt] * 0.1f + act[mt] * 0.005f;
      }
      xk[mt][0] = (ego_v[mt]                                      - mean[0]) * istd[0];
      xk[mt][1] = (fv                                             - mean[1]) * istd[1];
      xk[mt][2] = (ego_v[mt] - fv                                 - mean[2]) * istd[2];
      xk[mt][3] = (fgx - ego_x[mt]                                - mean[3]) * istd[3];
      xk[mt][4] = ((ego_v[mt] - mv) * ex                          - mean[4]) * istd[4];
      xk[mt][5] = ((mgx - ego_x[mt]) * ex + (1.0f - ex) * 100.0f  - mean[5]) * istd[5];
      xk[mt][6] = m0[mt]; xk[mt][7] = m1[mt]; xk[mt][8] = m2[mt];
    }
    // prefetch next step (hidden under MFMA)
    if (t + 1 < T) {
#pragma unroll
      for (int mt = 0; mt < 2; ++mt) {
        const float* ip = idmp[mt] + (t + 1) * 12;
        nsa[mt] = *(const v4f*)ip;  nfb[mt] = *(const v2f*)(ip + 4);  nex[mt] = ip[11];
        const float* mp = mrgp[mt] + (t + 1) * 3;
        nm0[mt] = mp[0]; nm1[mt] = mp[1]; nm2[mt] = mp[2];
      }
    }

    // ---- env A-frags: A[m][k=8gq+j] = env dim (8gq+j) of row m; dims 9..31 zero ----
    short8 eh[2], em[2];
#pragma unroll
    for (int mt = 0; mt < 2; ++mt) {
      uint32_t hi[8], mi[8];
#pragma unroll
      for (int j = 0; j < 8; ++j) {
        float v = (gq == 0) ? xk[mt][j] : ((gq == 1 && j == 0) ? xk[mt][8] : 0.f);
        split2(v, hi[j], mi[j]);
      }
      U8 uh, um;
#pragma unroll
      for (int d = 0; d < 4; ++d) {
        uh.u[d] = pack_hi16(hi[2*d+1], hi[2*d]);
        um.u[d] = pack_hi16(mi[2*d+1], mi[2*d]);
      }
      eh[mt] = uh.v; em[mt] = um.v;
    }

    v4f acc2[2][8];
#pragma unroll
    for (int mt = 0; mt < 2; ++mt)
#pragma unroll
      for (int nt = 0; nt < 8; ++nt)
        acc2[mt][nt] = (v4f){b2c[nt], b2c[nt], b2c[nt], b2c[nt]};

    // ---- fused layer1 -> h slice -> layer2, kt-sliced (h never fully materialized) ----
#pragma unroll
    for (int kt = 0; kt < 4; ++kt) {
      // layer-1 for output cols kt*32..kt*32+31 (nt = 2kt, 2kt+1)
#pragma unroll
      for (int mt = 0; mt < 2; ++mt)
#pragma unroll
        for (int ntl = 0; ntl < 2; ++ntl) {
          const int nt = kt * 2 + ntl;
          v4f a1 = *(const v4f*)&sBase[(wave*128 + nt*16 + o) * 36 + mt*16 + 4*gq];
          short8 bh = sEnvB[(nt*2 + 0) * 64 + lane];
          short8 bm = sEnvB[(nt*2 + 1) * 64 + lane];
          a1 = mfma16(eh[mt], bm, a1);
          a1 = mfma16(em[mt], bh, a1);
          a1 = mfma16(eh[mt], bh, a1);
#pragma unroll
          for (int r = 0; r < 4; ++r) {
            const float hv = fmaxf(a1[r], 0.f);
            uint32_t hi, mi; split2(hv, hi, mi);
            sH[(wave*32 + mt*16 + 4*gq + r) * 36 + ntl*16 + o] = hi | (mi >> 16);
          }
        }
      // read back as A-frags (wave-private; lgkmcnt orders RAW) + layer-2 MFMA
#pragma unroll
      for (int mt = 0; mt < 2; ++mt) {
        const uint32_t* src = &sH[(wave*32 + mt*16 + o) * 36 + gq*8];
        v4u q0 = *(const v4u*)src;
        v4u q1 = *(const v4u*)(src + 4);
        uint32_t u[8] = {q0[0], q0[1], q0[2], q0[3], q1[0], q1[1], q1[2], q1[3]};
        U8 uh, um;
#pragma unroll
        for (int d = 0; d < 4; ++d) {
          uh.u[d] = pack_hi16(u[2*d+1], u[2*d]);   // hi plane (top16 of packed)
          um.u[d] = pack_lo16(u[2*d+1], u[2*d]);   // mid plane (low16 of packed)
        }
        short8 ah = uh.v, am = um.v;
#pragma unroll
        for (int nt = 0; nt < 8; ++nt) {
          acc2[mt][nt] = mfma16(ah, w2m[kt*8 + nt], acc2[mt][nt]);
          acc2[mt][nt] = mfma16(am, w2h[kt*8 + nt], acc2[mt][nt]);
          acc2[mt][nt] = mfma16(ah, w2h[kt*8 + nt], acc2[mt][nt]);
        }
      }
    }

    // ---- layer 3: act = relu(h2) @ W3 + b3 ----
    float part[2][4];
#pragma unroll
    for (int mt = 0; mt < 2; ++mt)
#pragma unroll
      for (int r = 0; r < 4; ++r) part[mt][r] = 0.f;
#pragma unroll
    for (int mt = 0; mt < 2; ++mt)
#pragma unroll
      for (int nt = 0; nt < 8; ++nt) {
        v4f h = acc2[mt][nt];
#pragma unroll
        for (int r = 0; r < 4; ++r) part[mt][r] += fmaxf(h[r], 0.f) * W3c[nt];
      }
#pragma unroll
    for (int m = 1; m <= 8; m <<= 1)
#pragma unroll
      for (int mt = 0; mt < 2; ++mt)
#pragma unroll
        for (int r = 0; r < 4; ++r) part[mt][r] += __shfl_xor(part[mt][r], m, 64);

    const int src = ((o >> 2) << 4) | o;   // lane holding row o's partials
#pragma unroll
    for (int mt = 0; mt < 2; ++mt) {
      const float c0 = __shfl(part[mt][0], src, 64);
      const float c1 = __shfl(part[mt][1], src, 64);
      const float c2 = __shfl(part[mt][2], src, 64);
      const float c3 = __shfl(part[mt][3], src, 64);
      const float slo = (o & 1) ? c1 : c0;
      const float shi = (o & 1) ? c3 : c2;
      act[mt] = ((o & 2) ? shi : slo) + b3v;
    }

    if (gq == 0) {
      out[(size_t)(wave_row0 + o)      * T + t] = act[0];
      out[(size_t)(wave_row0 + 16 + o) * T + t] = act[1];
    }

    // roll prefetched inputs
#pragma unroll
    for (int mt = 0; mt < 2; ++mt) {
      sa[mt] = nsa[mt]; fb[mt] = nfb[mt]; exr[mt] = nex[mt];
      m0[mt] = nm0[mt]; m1[mt] = nm1[mt]; m2[mt] = nm2[mt];
    }
  }
}

}  // namespace

extern "C" void kernel_launch(void* const* d_in, const int* in_sizes, int n_in,
                              void* d_out, int out_size, void* d_ws, size_t ws_size,
                              hipStream_t stream) {
  const float* proj  = (const float*)d_in[0];
  const float* idm   = (const float*)d_in[1];
  const float* merg  = (const float*)d_in[2];
  const float* W1    = (const float*)d_in[3];
  const float* b1    = (const float*)d_in[4];
  const float* W2    = (const float*)d_in[5];
  const float* b2    = (const float*)d_in[6];
  const float* W3    = (const float*)d_in[7];
  const float* b3    = (const float*)d_in[8];
  const float* smean = (const float*)d_in[9];
  const float* svar  = (const float*)d_in[10];
  // d_in[11] = rollout_len (fixed 50)

  dim3 grid(NB / BLK_ROWS);   // 256 blocks -> 1 per CU, single pass
  dim3 block(NTHREADS);       // 256 threads = 4 waves x 32 rows
  hipLaunchKernelGGL(fwdsim4, grid, block, 0, stream,
                     proj, idm, merg, W1, b1, W2, b2, W3, b3, smean, svar,
                     (float*)d_out);
}